// Round 8
// baseline (133.720 us; speedup 1.0000x reference)
//
#include <hip/hip_runtime.h>

// LocallyConnected1d: out[b,o,i] = sum_{c,k} x[b,c,i+k] * w[o,c,i,k] + 64*bias[o,i]
// B=128, C_IN=64, C_OUT=64, L=1024, K=9, L_OUT=1016
//
// R8: pump-byte reduction. R7 measured AT the per-CU pump roofline (~6.3 TB/s over
// ALL moved bytes); biggest reducible item = A slab re-pumped by 4 o-blocks.
//   k1b: x -> xt2[l][cc][b][c8] bf16 (unchanged, ~8us, sector-clean).
//   kf3: OT=32 (grid 254 = 127 it x 2 ob): A-pump 130->65 MB.
//        A single-buffered via global_load_lds (linear dest); B single-buffered
//        bf16 LDS with slot = o ^ (e&31) swizzle; w 1-deep reg prefetch (9 f32x4,
//        issued top-of-iter, flies across COMPUTE, cvt'd bottom-of-iter).
//        acc[8][2] (64 VGPR) + wr 36 -> ~120 VGPR, launch_bounds(512,4), 2 blk/CU.

#define LIN  1024
#define LOUT 1016

typedef __attribute__((ext_vector_type(4))) float f32x4;
typedef __attribute__((ext_vector_type(8))) short bf16x8;

typedef const __attribute__((address_space(1))) unsigned int* gptr_t;
typedef __attribute__((address_space(3))) unsigned int* lptr_t;

static __device__ __forceinline__ unsigned short f2bf(float f) {
    unsigned int u = __float_as_uint(f);
    u += 0x7fffu + ((u >> 16) & 1u);   // round-to-nearest-even
    return (unsigned short)(u >> 16);
}

// ---------------- K1b: x[b][c][l] f32 -> xt2[(l*8+cc)*1024 + b*8 + c] bf16 ----------------
__global__ __launch_bounds__(512) void k1b(const float* __restrict__ x,
                                           unsigned short* __restrict__ xt2)
{
    __shared__ unsigned short T[16 * 1032 + 8];
    const int t    = threadIdx.x;
    const int lane = t & 63;
    const int wid  = t >> 6;
    const int lt   = (int)blockIdx.x >> 3;
    const int cc   = (int)blockIdx.x & 7;
    const int l0   = lt * 16;
    const int rl   = lane >> 2;
    const int pos  = lane & 3;

    #pragma unroll
    for (int s = 0; s < 8; ++s) {
        int r = s * 128 + wid * 16 + rl;
        int b = r >> 3, cl = r & 7;
        f32x4 v = *(const f32x4*)&x[(size_t)(b * 64 + cc * 8 + cl) * 1024 + l0 + pos * 4];
        #pragma unroll
        for (int j = 0; j < 4; ++j)
            T[(pos * 4 + j) * 1032 + b * 8 + cl] = f2bf(v[j]);
    }
    __syncthreads();
    #pragma unroll
    for (int j2 = 0; j2 < 4; ++j2) {
        int e = j2 * 512 + t;
        int l = e >> 7, m = e & 127;
        uint4 v = *(const uint4*)&T[l * 1032 + m * 8];
        *(uint4*)&xt2[((size_t)(l0 + l) * 8 + cc) * 1024 + m * 8] = v;
    }
}

// ---------------- KF3: fused GEMM, OT=32 ----------------
// LDS (70400 B): A @0 [16 row][128 b][8 c] bf16 = 32768 (linear, gload_lds dest)
//                B @32768 [72 e][32 o-slot][8 c] bf16 = 36864, slot = o ^ (e&31)
//                zslab @69632 768 B zeros; epilogue Cb[64][16][8] f32 overlays A.
__global__ __launch_bounds__(512, 4) void kf3(const unsigned short* __restrict__ xt2,
                                              const float* __restrict__ w,
                                              const float* __restrict__ bias,
                                              float* __restrict__ out)
{
    __shared__ __align__(16) char smem[70400];

    // bijective XCD-chunked swizzle over 254 blocks (q=31, r=6)
    const int orig = (int)blockIdx.x;
    const int xcd = orig & 7, sx = orig >> 3;
    const int vid = (xcd < 6) ? xcd * 32 + sx : 192 + (xcd - 6) * 31 + sx;
    const int it = vid >> 1, ob = vid & 1;
    const int i0 = it * 8, o0 = ob * 32;

    const int t    = threadIdx.x;
    const int wid  = t >> 6;          // wave = local i
    const int lane = t & 63;
    const int l16  = lane & 15, l4 = lane >> 4;

    // w staging role: run r = (ow, cl), 2 lanes/run, lane-half h covers 4 i x 9 k
    const int wrun = t >> 1, h = t & 1;
    const int ow = wrun >> 3, cl = wrun & 7;

    // zero slab
    if (t < 192) *(unsigned int*)(smem + 69632 + t * 4) = 0u;

    f32x4 acc[8][2];
    #pragma unroll
    for (int m = 0; m < 8; ++m) {
        acc[m][0] = (f32x4){0.f, 0.f, 0.f, 0.f};
        acc[m][1] = (f32x4){0.f, 0.f, 0.f, 0.f};
    }

    f32x4 wr[9];   // 36 floats = (4 i) x (9 k) for this lane's half-run

#define ISSUE_W(ccw) { \
        const float* rb = w + (size_t)((o0 + ow) * 64 + (ccw) * 8 + cl) * 9144 \
                            + (size_t)i0 * 9 + h * 36; \
        _Pragma("unroll") \
        for (int v = 0; v < 9; ++v) wr[v] = *(const f32x4*)(rb + v * 4); \
    }

#define CVT_W() { \
        unsigned short* Bd = (unsigned short*)(smem + 32768); \
        _Pragma("unroll") \
        for (int v = 0; v < 9; ++v) { \
            _Pragma("unroll") \
            for (int j = 0; j < 4; ++j) { \
                const int f  = v * 4 + j; \
                const int ii = f / 9, kk = f - 9 * (f / 9); \
                const int e  = (h * 4 + ii) * 9 + kk; \
                Bd[(e * 32 + (ow ^ (e & 31))) * 8 + cl] = f2bf(wr[v][j]); \
            } \
        } \
    }

#define ISSUE_A(cca) { \
        _Pragma("unroll") \
        for (int jj = 0; jj < 4; ++jj) { \
            int jA = wid * 4 + jj; \
            const unsigned short* src = xt2 + ((size_t)(i0 + (jA >> 1)) * 8 + (cca)) * 1024 \
                                            + (jA & 1) * 512 + lane * 8; \
            __builtin_amdgcn_global_load_lds((gptr_t)(const void*)src, \
                (lptr_t)(void*)(smem + jA * 1024), 16, 0, 0); \
        } \
    }

#define COMPUTE() { \
        _Pragma("unroll") \
        for (int kp = 0; kp < 3; ++kp) { \
            const int kb = kp * 4 + l4; \
            const int e  = wid * 9 + kb; \
            const char* b0a; const char* b1a; \
            if (kb < 9) { \
                b0a = smem + 32768 + ((e * 32 + (l16 ^ (e & 31))) * 8) * 2; \
                b1a = smem + 32768 + ((e * 32 + ((16 + l16) ^ (e & 31))) * 8) * 2; \
            } else { \
                b0a = smem + 69632 + ((kb - 9) * 16 + l16) * 16; \
                b1a = b0a; \
            } \
            bf16x8 bf0 = *(const bf16x8*)b0a; \
            bf16x8 bf1 = *(const bf16x8*)b1a; \
            int rowc = wid + kb; rowc = rowc > 15 ? 15 : rowc; \
            const char* arow = smem + (rowc * 128 + l16) * 16; \
            _Pragma("unroll") \
            for (int m = 0; m < 8; ++m) { \
                bf16x8 af = *(const bf16x8*)(arow + (m << 8)); \
                acc[m][0] = __builtin_amdgcn_mfma_f32_16x16x32_bf16(af, bf0, acc[m][0], 0, 0, 0); \
                acc[m][1] = __builtin_amdgcn_mfma_f32_16x16x32_bf16(af, bf1, acc[m][1], 0, 0, 0); \
            } \
        } \
    }

    // ---- prologue ----
    ISSUE_W(0);
    __builtin_amdgcn_sched_barrier(0);
    ISSUE_A(0);
    __builtin_amdgcn_sched_barrier(0);
    CVT_W();                                     // auto-drains w(0) (vmcnt(4): A outstanding)
    asm volatile("s_waitcnt vmcnt(0)" ::: "memory");
    asm volatile("s_waitcnt lgkmcnt(0)" ::: "memory");
    __builtin_amdgcn_sched_barrier(0);
    __builtin_amdgcn_s_barrier();

    for (int cc = 0; cc < 8; ++cc) {
        if (cc < 7) {                             // w(cc+1) flies across COMPUTE
            ISSUE_W(cc + 1);
            __builtin_amdgcn_sched_barrier(0);
        }
        COMPUTE();
        __builtin_amdgcn_sched_barrier(0);
        __builtin_amdgcn_s_barrier();             // all waves done reading A, B
        if (cc < 7) {
            ISSUE_A(cc + 1);                      // overwrite A (safe post-barrier)
            __builtin_amdgcn_sched_barrier(0);
            CVT_W();                              // auto vmcnt(4) drains w(cc+1), A stays
            asm volatile("s_waitcnt vmcnt(0)" ::: "memory");   // A landed
            asm volatile("s_waitcnt lgkmcnt(0)" ::: "memory"); // B writes visible
            __builtin_amdgcn_sched_barrier(0);
            __builtin_amdgcn_s_barrier();
        }
    }

    // ---- epilogue: 4 quarter-passes (2 b-halves x 2 o-halves) ----
    // C/D layout (m89): col = lane&15 (=o within 16), row = (lane>>4)*4 + reg (=b)
    __syncthreads();                              // A region dead for all waves
    float* Cb = (float*)smem;                     // [64 b][16 o][8 i]
    #pragma unroll
    for (int p = 0; p < 2; ++p) {
        #pragma unroll
        for (int nf = 0; nf < 2; ++nf) {
            if (p | nf) __syncthreads();
            #pragma unroll
            for (int mm = 0; mm < 4; ++mm) {
                #pragma unroll
                for (int j = 0; j < 4; ++j) {
                    const int b_loc = mm * 16 + l4 * 4 + j;
                    Cb[(b_loc * 16 + l16) * 8 + wid] = acc[p * 4 + mm][nf][j];
                }
            }
            __syncthreads();
            #pragma unroll
            for (int s2 = 0; s2 < 2; ++s2) {
                const int e = t * 2 + s2;
                const int b_loc = e >> 4, o = e & 15;
                const float* cb = &Cb[(b_loc * 16 + o) * 8];
                f32x4 v0 = *(const f32x4*)cb;
                f32x4 v1 = *(const f32x4*)(cb + 4);
                const float* bp = &bias[(size_t)(o0 + nf * 16 + o) * LOUT + i0];
                f32x4 bv0 = *(const f32x4*)bp;
                f32x4 bv1 = *(const f32x4*)(bp + 4);
                float* op = &out[((size_t)(p * 64 + b_loc) * 64 + o0 + nf * 16 + o) * LOUT + i0];
                *(f32x4*)op       = v0 + 64.0f * bv0;
                *(f32x4*)(op + 4) = v1 + 64.0f * bv1;
            }
        }
    }
#undef ISSUE_W
#undef CVT_W
#undef ISSUE_A
#undef COMPUTE
}

// ---------------- fallback (tiny ws): direct scattered-read GEMM ----------------
__global__ __launch_bounds__(512, 4) void lc1d_legacy(
    const float* __restrict__ x, const float* __restrict__ w,
    const float* __restrict__ bias, float* __restrict__ out)
{
    const int i    = ((int)(blockIdx.x & 7)) * 127 + ((int)blockIdx.x >> 3);
    const int tid  = threadIdx.x;
    const int lane = tid & 63;
    const int wid  = tid >> 6;
    const int wm   = wid >> 1;
    const int wn   = wid & 1;
    const int l16  = lane & 15;
    const int l4   = lane >> 4;

    __shared__ unsigned short Alds[128][40];
    __shared__ unsigned short Blds[64][40];

    f32x4 acc[2][2];
    #pragma unroll
    for (int a = 0; a < 2; ++a)
        #pragma unroll
        for (int b = 0; b < 2; ++b)
            acc[a][b] = (f32x4){0.f, 0.f, 0.f, 0.f};

    for (int tch = 0; tch < 18; ++tch) {
        const int q0 = tch * 32;
        #pragma unroll
        for (int j = 0; j < 4; ++j) {
            int e = tid + j * 512;
            int o = e >> 5, qq = e & 31;
            int q = q0 + qq;
            int c = q / 9, k = q - 9 * c;
            Blds[o][qq] = f2bf(w[((size_t)(o * 64 + c) * LOUT + i) * 9 + k]);
        }
        #pragma unroll
        for (int j = 0; j < 8; ++j) {
            int e = tid + j * 512;
            int b = e >> 5, qq = e & 31;
            int q = q0 + qq;
            int c = q / 9, k = q - 9 * c;
            Alds[b][qq] = f2bf(x[(size_t)(b * 64 + c) * LIN + i + k]);
        }
        __syncthreads();
        bf16x8 af[2], bfr[2];
        #pragma unroll
        for (int mf = 0; mf < 2; ++mf)
            af[mf] = *reinterpret_cast<const bf16x8*>(&Alds[wm * 32 + mf * 16 + l16][l4 * 8]);
        #pragma unroll
        for (int nf = 0; nf < 2; ++nf)
            bfr[nf] = *reinterpret_cast<const bf16x8*>(&Blds[wn * 32 + nf * 16 + l16][l4 * 8]);
        #pragma unroll
        for (int mf = 0; mf < 2; ++mf)
            #pragma unroll
            for (int nf = 0; nf < 2; ++nf)
                acc[mf][nf] = __builtin_amdgcn_mfma_f32_16x16x32_bf16(af[mf], bfr[nf], acc[mf][nf], 0, 0, 0);
        __syncthreads();
    }
    #pragma unroll
    for (int nf = 0; nf < 2; ++nf) {
        int o = wn * 32 + nf * 16 + l16;
        float bv = 64.0f * bias[o * LOUT + i];
        #pragma unroll
        for (int mf = 0; mf < 2; ++mf)
            #pragma unroll
            for (int j = 0; j < 4; ++j) {
                int b = wm * 32 + mf * 16 + l4 * 4 + j;
                out[((size_t)b * 64 + o) * LOUT + i] = acc[mf][nf][j] + bv;
            }
    }
}

extern "C" void kernel_launch(void* const* d_in, const int* in_sizes, int n_in,
                              void* d_out, int out_size, void* d_ws, size_t ws_size,
                              hipStream_t stream) {
    const float* x    = (const float*)d_in[0];
    const float* w    = (const float*)d_in[1];
    const float* bias = (const float*)d_in[2];
    float* out        = (float*)d_out;

    const size_t XTB = (size_t)1024 * 8192 * 2;   // 16,777,216

    if (ws_size < XTB) {
        lc1d_legacy<<<dim3(LOUT), dim3(512), 0, stream>>>(x, w, bias, out);
        return;
    }
    unsigned short* xt2 = (unsigned short*)d_ws;

    k1b<<<dim3(512), dim3(512), 0, stream>>>(x, xt2);
    kf3<<<dim3(254), dim3(512), 0, stream>>>(xt2, w, bias, out);
}

// Round 9
// 90.306 us; speedup vs baseline: 1.4807x; 1.4807x over previous
//
#include <hip/hip_runtime.h>

// LocallyConnected1d: out[b,o,i] = sum_{c,k} x[b,c,i+k] * w[o,c,i,k] + 64*bias[o,i]
// B=128, C_IN=64, C_OUT=64, L=1024, K=9, L_OUT=1016
//
// R9: OT=32 with a 1-block/CU-safe deep pipeline (R8 failed on drain-per-iter +
// lost co-residency, NOT on the tiling).
//   k1b: x -> xt2[l][cc][b][c8] bf16 (unchanged, ~8us, sector-clean).
//   kf4: 1024 thr (16 waves = (i_loc 0..7, o-half)), IT=8, OT=32, grid 254.
//        A double-buf via global_load_lds (2x32KB), B double-buf bf16 (2x36.9KB),
//        W regs 2-deep (5 uniform f32x4 ops/thread -> deterministic vmcnt ledger).
//        One raw s_barrier/iter; vmcnt(7)/vmcnt(5) counted waits; never 0 mid-loop.
//        Pump: A 65 + w 167 + out 40 ~= 277 MB (R7 was ~350).

#define LIN  1024
#define LOUT 1016

typedef __attribute__((ext_vector_type(4))) float f32x4;
typedef __attribute__((ext_vector_type(2))) float f32x2;
typedef __attribute__((ext_vector_type(8))) short bf16x8;

typedef const __attribute__((address_space(1))) unsigned int* gptr_t;
typedef __attribute__((address_space(3))) unsigned int* lptr_t;

static __device__ __forceinline__ unsigned short f2bf(float f) {
    unsigned int u = __float_as_uint(f);
    u += 0x7fffu + ((u >> 16) & 1u);   // round-to-nearest-even
    return (unsigned short)(u >> 16);
}

// ---------------- K1b: x[b][c][l] f32 -> xt2[(l*8+cc)*1024 + b*8 + c] bf16 ----------------
__global__ __launch_bounds__(512) void k1b(const float* __restrict__ x,
                                           unsigned short* __restrict__ xt2)
{
    __shared__ unsigned short T[16 * 1032 + 8];
    const int t    = threadIdx.x;
    const int lane = t & 63;
    const int wid  = t >> 6;
    const int lt   = (int)blockIdx.x >> 3;
    const int cc   = (int)blockIdx.x & 7;
    const int l0   = lt * 16;
    const int rl   = lane >> 2;
    const int pos  = lane & 3;

    #pragma unroll
    for (int s = 0; s < 8; ++s) {
        int r = s * 128 + wid * 16 + rl;
        int b = r >> 3, cle = r & 7;
        f32x4 v = *(const f32x4*)&x[(size_t)(b * 64 + cc * 8 + cle) * 1024 + l0 + pos * 4];
        #pragma unroll
        for (int j = 0; j < 4; ++j)
            T[(pos * 4 + j) * 1032 + b * 8 + cle] = f2bf(v[j]);
    }
    __syncthreads();
    #pragma unroll
    for (int j2 = 0; j2 < 4; ++j2) {
        int e = j2 * 512 + t;
        int l = e >> 7, m = e & 127;
        uint4 v = *(const uint4*)&T[l * 1032 + m * 8];
        *(uint4*)&xt2[((size_t)(l0 + l) * 8 + cc) * 1024 + m * 8] = v;
    }
}

// ---------------- KF4: fused GEMM, OT=32, 16-wave deep pipeline ----------------
// LDS 140032 B: A0 @0, A1 @32768 (each [16 row][128 b][8 c] bf16 = 32768)
//               B0 @65536, B1 @102400 (each [72 e][32 slot][8 c] bf16 = 36864, slot=o^(e&31))
//               zslab @139264 (768 B). Epilogue Cb[64][32][8] f32 overlays A0+A1.
#define SB() __builtin_amdgcn_sched_barrier(0)
#define WVM(n) asm volatile("s_waitcnt vmcnt(" #n ")" ::: "memory")
#define WLG()  asm volatile("s_waitcnt lgkmcnt(0)" ::: "memory")

__global__ __launch_bounds__(1024, 4) void kf4(const unsigned short* __restrict__ xt2,
                                               const float* __restrict__ w,
                                               const float* __restrict__ bias,
                                               float* __restrict__ out)
{
    __shared__ __align__(16) char smem[140032];

    // bijective XCD-chunked swizzle over 254 blocks (q=31, r=6)
    const int orig = (int)blockIdx.x;
    const int xcd = orig & 7, sx = orig >> 3;
    const int vid = (xcd < 6) ? xcd * 32 + sx : 192 + (xcd - 6) * 31 + sx;
    const int it = vid >> 1, ob = vid & 1;
    const int i0 = it * 8, o0 = ob * 32;

    const int t    = threadIdx.x;
    const int wid  = t >> 6;                 // 0..15
    const int lane = t & 63;
    const int l16  = lane & 15, l4 = lane >> 4;
    const int i_loc = wid >> 1, oh = wid & 1;
    const int ow = t >> 5;                   // 0..31  (w-run o index)
    const int cl = (t >> 2) & 7;             // 0..7   (w-run c index)
    const int p  = t & 3;                    // granule phase
    const int g5 = (p < 2) ? 16 + p : p;     // 5th granule (dummy for p>=2)

    if (t < 192) *(unsigned int*)(smem + 139264 + t * 4) = 0u;   // zslab

    f32x4 acc[8];
    #pragma unroll
    for (int m = 0; m < 8; ++m) acc[m] = (f32x4){0.f, 0.f, 0.f, 0.f};

    f32x4 wr4[2][4];
    f32x4 wr5[2];

#define ISSUE_W(slot, ccw) { \
        const float* rb = w + (size_t)((o0 + ow) * 64 + (ccw) * 8 + cl) * 9144 + (size_t)i0 * 9; \
        wr4[slot][0] = *(const f32x4*)(rb + 4 * p); \
        wr4[slot][1] = *(const f32x4*)(rb + 16 + 4 * p); \
        wr4[slot][2] = *(const f32x4*)(rb + 32 + 4 * p); \
        wr4[slot][3] = *(const f32x4*)(rb + 48 + 4 * p); \
        wr5[slot]    = *(const f32x4*)(rb + 4 * g5); \
    }

#define CVT_W(slot, buf) { \
        unsigned short* Bd = (unsigned short*)(smem + 65536 + (buf) * 36864); \
        _Pragma("unroll") \
        for (int v = 0; v < 4; ++v) { \
            _Pragma("unroll") \
            for (int jj = 0; jj < 4; ++jj) { \
                const int e = 16 * v + 4 * p + jj; \
                Bd[(e * 32 + (ow ^ (e & 31))) * 8 + cl] = f2bf(wr4[slot][v][jj]); \
            } \
        } \
        if (p < 2) { \
            _Pragma("unroll") \
            for (int jj = 0; jj < 4; ++jj) { \
                const int e = 64 + 4 * p + jj; \
                Bd[(e * 32 + (ow ^ (e & 31))) * 8 + cl] = f2bf(wr5[slot][jj]); \
            } \
        } \
    }

#define ISSUE_A(cca, abuf) { \
        _Pragma("unroll") \
        for (int j = 0; j < 2; ++j) { \
            const int jA = wid + j * 16; \
            const int row = jA >> 1, half = jA & 1; \
            const unsigned short* src = xt2 + ((size_t)(i0 + row) * 8 + (cca)) * 1024 \
                                            + half * 512 + lane * 8; \
            __builtin_amdgcn_global_load_lds((gptr_t)(const void*)src, \
                (lptr_t)(void*)(smem + (abuf) * 32768 + row * 2048 + half * 1024), 16, 0, 0); \
        } \
    }

#define COMPUTE(abuf, bbuf) { \
        const char* Ab = smem + (abuf) * 32768; \
        const char* Bb = smem + 65536 + (bbuf) * 36864; \
        _Pragma("unroll") \
        for (int kp = 0; kp < 3; ++kp) { \
            const int kb = kp * 4 + l4; \
            const int e  = i_loc * 9 + kb; \
            const char* baddr = (kb < 9) \
                ? (Bb + ((e * 32 + ((oh * 16 + l16) ^ (e & 31))) << 4)) \
                : (smem + 139264 + (((kb - 9) * 16 + l16) << 4)); \
            bf16x8 bfr = *(const bf16x8*)baddr; \
            const int rowc = i_loc + (kb < 9 ? kb : 8); \
            const char* arow = Ab + (rowc << 11); \
            _Pragma("unroll") \
            for (int m = 0; m < 8; ++m) { \
                bf16x8 af = *(const bf16x8*)(arow + ((m * 16 + l16) << 4)); \
                acc[m] = __builtin_amdgcn_mfma_f32_16x16x32_bf16(af, bfr, acc[m], 0, 0, 0); \
            } \
        } \
    }

    // ---- prologue:  in-flight ledger (per thread): A=2 ops, W=5 ops ----
    SB(); ISSUE_A(0, 0); SB();
    ISSUE_W(0, 0); SB();
    ISSUE_W(1, 1); SB();
    WVM(5); SB();                 // drain A(0)+W(0); W(1)=5 stays
    CVT_W(0, 0);
    WLG(); SB();
    __builtin_amdgcn_s_barrier(); SB();

#define ITER(cc) { \
        SB(); ISSUE_A((cc) + 1, ((cc) + 1) & 1); SB(); \
        ISSUE_W((cc) & 1, (cc) + 2); SB(); \
        WVM(7); SB();             /* drain W(cc+1); keep A(cc+1)=2, W(cc+2)=5 */ \
        CVT_W(((cc) + 1) & 1, ((cc) + 1) & 1); \
        COMPUTE((cc) & 1, (cc) & 1); \
        SB(); WVM(5); SB();       /* drain A(cc+1); keep W(cc+2)=5 */ \
        WLG(); SB(); \
        __builtin_amdgcn_s_barrier(); SB(); \
    }

    ITER(0) ITER(1) ITER(2) ITER(3) ITER(4) ITER(5)

    // iter 6: no W(8); carried {W(7):5} + A(7):2
    SB(); ISSUE_A(7, 1); SB();
    WVM(2); SB();                 // drain W(7); keep A(7)=2
    CVT_W(1, 1);
    COMPUTE(0, 0);
    SB(); WVM(0); SB();           // drain A(7)
    WLG(); SB();
    __builtin_amdgcn_s_barrier(); SB();

    // iter 7
    COMPUTE(1, 1);
    __syncthreads();

    // ---- epilogue: acc -> Cb[64 b][32 o][8 i] f32 (overlays A0+A1), 32-B i-run stores ----
    // C/D layout (m89): col = lane&15 (=o within 16), row = (lane>>4)*4 + reg (=b)
    float* Cb = (float*)smem;
    #pragma unroll
    for (int pq = 0; pq < 2; ++pq) {
        if (pq) __syncthreads();
        #pragma unroll
        for (int mm = 0; mm < 4; ++mm) {
            #pragma unroll
            for (int j = 0; j < 4; ++j) {
                const int b_loc = mm * 16 + l4 * 4 + j;
                Cb[(b_loc * 32 + oh * 16 + l16) * 8 + i_loc] = acc[pq * 4 + mm][j];
            }
        }
        __syncthreads();
        #pragma unroll
        for (int s2 = 0; s2 < 2; ++s2) {
            const int e = t * 2 + s2;
            const int b_loc = e >> 5, o = e & 31;
            const float* cb = &Cb[(b_loc * 32 + o) * 8];
            f32x4 v0 = *(const f32x4*)cb;
            f32x4 v1 = *(const f32x4*)(cb + 4);
            const float* bp = &bias[(size_t)(o0 + o) * LOUT + i0];
            f32x4 bv0 = *(const f32x4*)bp;
            f32x4 bv1 = *(const f32x4*)(bp + 4);
            float* op = &out[((size_t)(pq * 64 + b_loc) * 64 + o0 + o) * LOUT + i0];
            *(f32x4*)op       = v0 + 64.0f * bv0;
            *(f32x4*)(op + 4) = v1 + 64.0f * bv1;
        }
    }
#undef ISSUE_W
#undef CVT_W
#undef ISSUE_A
#undef COMPUTE
#undef ITER
}

// ---------------- fallback (tiny ws): direct scattered-read GEMM ----------------
__global__ __launch_bounds__(512, 4) void lc1d_legacy(
    const float* __restrict__ x, const float* __restrict__ w,
    const float* __restrict__ bias, float* __restrict__ out)
{
    const int i    = ((int)(blockIdx.x & 7)) * 127 + ((int)blockIdx.x >> 3);
    const int tid  = threadIdx.x;
    const int lane = tid & 63;
    const int wid  = tid >> 6;
    const int wm   = wid >> 1;
    const int wn   = wid & 1;
    const int l16  = lane & 15;
    const int l4   = lane >> 4;

    __shared__ unsigned short Alds[128][40];
    __shared__ unsigned short Blds[64][40];

    f32x4 acc[2][2];
    #pragma unroll
    for (int a = 0; a < 2; ++a)
        #pragma unroll
        for (int b = 0; b < 2; ++b)
            acc[a][b] = (f32x4){0.f, 0.f, 0.f, 0.f};

    for (int tch = 0; tch < 18; ++tch) {
        const int q0 = tch * 32;
        #pragma unroll
        for (int j = 0; j < 4; ++j) {
            int e = tid + j * 512;
            int o = e >> 5, qq = e & 31;
            int q = q0 + qq;
            int c = q / 9, k = q - 9 * c;
            Blds[o][qq] = f2bf(w[((size_t)(o * 64 + c) * LOUT + i) * 9 + k]);
        }
        #pragma unroll
        for (int j = 0; j < 8; ++j) {
            int e = tid + j * 512;
            int b = e >> 5, qq = e & 31;
            int q = q0 + qq;
            int c = q / 9, k = q - 9 * c;
            Alds[b][qq] = f2bf(x[(size_t)(b * 64 + c) * LIN + i + k]);
        }
        __syncthreads();
        bf16x8 af[2], bfr[2];
        #pragma unroll
        for (int mf = 0; mf < 2; ++mf)
            af[mf] = *reinterpret_cast<const bf16x8*>(&Alds[wm * 32 + mf * 16 + l16][l4 * 8]);
        #pragma unroll
        for (int nf = 0; nf < 2; ++nf)
            bfr[nf] = *reinterpret_cast<const bf16x8*>(&Blds[wn * 32 + nf * 16 + l16][l4 * 8]);
        #pragma unroll
        for (int mf = 0; mf < 2; ++mf)
            #pragma unroll
            for (int nf = 0; nf < 2; ++nf)
                acc[mf][nf] = __builtin_amdgcn_mfma_f32_16x16x32_bf16(af[mf], bfr[nf], acc[mf][nf], 0, 0, 0);
        __syncthreads();
    }
    #pragma unroll
    for (int nf = 0; nf < 2; ++nf) {
        int o = wn * 32 + nf * 16 + l16;
        float bv = 64.0f * bias[o * LOUT + i];
        #pragma unroll
        for (int mf = 0; mf < 2; ++mf)
            #pragma unroll
            for (int j = 0; j < 4; ++j) {
                int b = wm * 32 + mf * 16 + l4 * 4 + j;
                out[((size_t)b * 64 + o) * LOUT + i] = acc[mf][nf][j] + bv;
            }
    }
}

extern "C" void kernel_launch(void* const* d_in, const int* in_sizes, int n_in,
                              void* d_out, int out_size, void* d_ws, size_t ws_size,
                              hipStream_t stream) {
    const float* x    = (const float*)d_in[0];
    const float* w    = (const float*)d_in[1];
    const float* bias = (const float*)d_in[2];
    float* out        = (float*)d_out;

    const size_t XTB = (size_t)1024 * 8192 * 2;   // 16,777,216

    if (ws_size < XTB) {
        lc1d_legacy<<<dim3(LOUT), dim3(512), 0, stream>>>(x, w, bias, out);
        return;
    }
    unsigned short* xt2 = (unsigned short*)d_ws;

    k1b<<<dim3(512), dim3(512), 0, stream>>>(x, xt2);
    kf4<<<dim3(254), dim3(1024), 0, stream>>>(xt2, w, bias, out);
}

// Round 10
// 61.138 us; speedup vs baseline: 2.1872x; 1.4771x over previous
//
#include <hip/hip_runtime.h>

// LocallyConnected1d: out[b,o,i] = sum_{c,k} x[b,c,i+k] * w[o,c,i,k] + 64*bias[o,i]
// B=128, C_IN=64, C_OUT=64, L=1024, K=9, L_OUT=1016
//
// R10 = R7 restore (measured best: 61.5 us; kf2 within ~3% of the per-CU pump
// ceiling for its ~350 MB of moved bytes; k1b sector-clean at ~6 TB/s).
// R8/R9 proved the OT=32 traffic saving is unharvestable: grid 254 < 256 CUs
// forces 1 block/CU, and a barrier'd single block eats HBM queueing jitter
// directly (153 / 111 us). Keep 508-block grid = 2 blocks/CU co-residency.
//   k1b: x[b][c][l] -> xt2[l][cc][b][c8] bf16, sector-clean both sides.
//   kf2: block = 8i x 16o x 128b; A via global_load_lds (linear, coalesced from
//        xt2); w direct f32 (288-B runs, 4-lanes-per-run role = full sectors),
//        reg->cvt->swizzled ds_write into double-buffered B; counted vmcnt(5);
//        epilogue LDS-transpose -> 32-B i-run stores.

#define LIN  1024
#define LOUT 1016

typedef __attribute__((ext_vector_type(4))) float f32x4;
typedef __attribute__((ext_vector_type(8))) short bf16x8;

typedef const __attribute__((address_space(1))) unsigned int* gptr_t;
typedef __attribute__((address_space(3))) unsigned int* lptr_t;

static __device__ __forceinline__ unsigned short f2bf(float f) {
    unsigned int u = __float_as_uint(f);
    u += 0x7fffu + ((u >> 16) & 1u);   // round-to-nearest-even
    return (unsigned short)(u >> 16);
}

// ---------------- K1b: x[b][c][l] f32 -> xt2[(l*8+cc)*1024 + b*8 + c] bf16 ----------------
// grid 512 = 64 l-tiles(16) x 8 c-chunks. Reads: 64-B runs, 4 lanes/run (full sectors).
__global__ __launch_bounds__(512) void k1b(const float* __restrict__ x,
                                           unsigned short* __restrict__ xt2)
{
    __shared__ unsigned short T[16 * 1032 + 8];   // [l][b*8+c], l-stride 1032 (bank skew)
    const int t    = threadIdx.x;
    const int lane = t & 63;
    const int wid  = t >> 6;
    const int lt   = (int)blockIdx.x >> 3;
    const int cc   = (int)blockIdx.x & 7;
    const int l0   = lt * 16;
    const int rl   = lane >> 2;      // run-local 0..15
    const int pos  = lane & 3;

    #pragma unroll
    for (int s = 0; s < 8; ++s) {
        int r = s * 128 + wid * 16 + rl;          // 0..1023 : (b, c_local)
        int b = r >> 3, cl = r & 7;
        f32x4 v = *(const f32x4*)&x[(size_t)(b * 64 + cc * 8 + cl) * 1024 + l0 + pos * 4];
        #pragma unroll
        for (int j = 0; j < 4; ++j)
            T[(pos * 4 + j) * 1032 + b * 8 + cl] = f2bf(v[j]);
    }
    __syncthreads();
    #pragma unroll
    for (int j2 = 0; j2 < 4; ++j2) {
        int e = j2 * 512 + t;                     // uint4 index 0..2047
        int l = e >> 7, m = e & 127;
        uint4 v = *(const uint4*)&T[l * 1032 + m * 8];
        *(uint4*)&xt2[((size_t)(l0 + l) * 8 + cc) * 1024 + m * 8] = v;
    }
}

// ---------------- KF2: fused GEMM ----------------
// LDS: A @0 [16 row][128 b][8 c] bf16 = 32768 (linear, gload_lds dest)
//      B @32768: 2 bufs x [e=i*9+k][16 o-slot][8 c] (slot = o ^ (e&15)) = 2x18432
//      zslab @69632: 768 B zeros (kb 9..11 fragment reads)
//      epilogue Cb overlays A (32 KB)
__global__ __launch_bounds__(512, 4) void kf2(const unsigned short* __restrict__ xt2,
                                              const float* __restrict__ w,
                                              const float* __restrict__ bias,
                                              float* __restrict__ out)
{
    __shared__ __align__(16) char smem[70400];

    // bijective XCD-chunked swizzle over 508 blocks (q=63, r=4)
    const int orig = (int)blockIdx.x;
    const int xcd = orig & 7, sx = orig >> 3;
    const int vid = (xcd < 4) ? xcd * 64 + sx : 256 + (xcd - 4) * 63 + sx;
    const int it = vid >> 2, ob = vid & 3;
    const int i0 = it * 8, o0 = ob * 16;

    const int t    = threadIdx.x;
    const int wid  = t >> 6;          // wave = local i
    const int lane = t & 63;
    const int l16  = lane & 15, l4 = lane >> 4;

    // w staging role: run (ow, cl), 4 lanes per run
    const int ow  = wid * 2 + (lane >> 5);     // 0..15
    const int cl  = (lane >> 2) & 7;           // 0..7
    const int pos = lane & 3;

    // zero slab init
    if (t < 192) *(unsigned int*)(smem + 69632 + t * 4) = 0u;

    f32x4 acc[8];
    #pragma unroll
    for (int m = 0; m < 8; ++m) acc[m] = (f32x4){0.f, 0.f, 0.f, 0.f};

    f32x4 wreg[2][5];

#define ISSUE_W(slot, ccw) { \
        const float* rb = w + (size_t)((o0 + ow) * 64 + (ccw) * 8 + cl) * 9144 + (size_t)i0 * 9; \
        wreg[slot][0] = *(const f32x4*)(rb + pos * 4); \
        wreg[slot][1] = *(const f32x4*)(rb + 16 + pos * 4); \
        wreg[slot][2] = *(const f32x4*)(rb + 32 + pos * 4); \
        wreg[slot][3] = *(const f32x4*)(rb + 48 + pos * 4); \
        if (pos < 2) wreg[slot][4] = *(const f32x4*)(rb + 64 + pos * 4); \
    }

#define CVT_W(slot, buf) { \
        unsigned short* Bd = (unsigned short*)(smem + 32768 + (buf) * 18432); \
        _Pragma("unroll") \
        for (int sv = 0; sv < 4; ++sv) { \
            _Pragma("unroll") \
            for (int j = 0; j < 4; ++j) { \
                int e = sv * 16 + pos * 4 + j; \
                Bd[e * 128 + ((ow ^ (e & 15)) << 3) + cl] = f2bf(wreg[slot][sv][j]); \
            } \
        } \
        if (pos < 2) { \
            _Pragma("unroll") \
            for (int j = 0; j < 4; ++j) { \
                int e = 64 + pos * 4 + j; \
                Bd[e * 128 + ((ow ^ (e & 15)) << 3) + cl] = f2bf(wreg[slot][4][j]); \
            } \
        } \
    }

#define ISSUE_A(cca) { \
        _Pragma("unroll") \
        for (int jj = 0; jj < 4; ++jj) { \
            int jA = wid * 4 + jj; \
            const unsigned short* src = xt2 + ((size_t)(i0 + (jA >> 1)) * 8 + (cca)) * 1024 \
                                            + (jA & 1) * 512 + lane * 8; \
            __builtin_amdgcn_global_load_lds((gptr_t)(const void*)src, \
                (lptr_t)(void*)(smem + jA * 1024), 16, 0, 0); \
        } \
    }

#define COMPUTE(buf) { \
        _Pragma("unroll") \
        for (int kp = 0; kp < 3; ++kp) { \
            const int kb = kp * 4 + l4; \
            const int e  = wid * 9 + kb; \
            const char* baddr = (kb < 9) \
                ? (smem + 32768 + (buf) * 18432 + (e * 128 + ((l16 ^ (e & 15)) << 3)) * 2) \
                : (smem + 69632 + ((kb - 9) * 16 + l16) * 16); \
            bf16x8 bfr = *(const bf16x8*)baddr; \
            int rowc = wid + kb; rowc = rowc > 15 ? 15 : rowc; \
            const char* arow = smem + (rowc * 128 + l16) * 16; \
            _Pragma("unroll") \
            for (int m = 0; m < 8; ++m) { \
                bf16x8 af = *(const bf16x8*)(arow + (m << 8)); \
                acc[m] = __builtin_amdgcn_mfma_f32_16x16x32_bf16(af, bfr, acc[m], 0, 0, 0); \
            } \
        } \
    }

    // prologue
    ISSUE_A(0);
    ISSUE_W(0, 0);
    ISSUE_W(1, 1);
    CVT_W(0, 0);                                  // compiler drains w(0) (A drains too)
    asm volatile("s_waitcnt vmcnt(5)" ::: "memory");
    asm volatile("s_waitcnt lgkmcnt(0)" ::: "memory");
    __builtin_amdgcn_sched_barrier(0);
    __builtin_amdgcn_s_barrier();

    #pragma unroll
    for (int cc = 0; cc < 8; ++cc) {
        COMPUTE(cc & 1);
        __builtin_amdgcn_sched_barrier(0);
        __builtin_amdgcn_s_barrier();             // all reads of A & B[cc&1] done
        if (cc < 7) {
            ISSUE_A(cc + 1);                      // oldest outstanding -> drained by vmcnt(5)
            if (cc < 6) ISSUE_W(cc & 1, cc + 2);  // newest; stays in flight
            CVT_W((cc + 1) & 1, (cc + 1) & 1);    // compiler auto-drains w(cc+1)
            if (cc < 6) { asm volatile("s_waitcnt vmcnt(5)" ::: "memory"); }
            else        { asm volatile("s_waitcnt vmcnt(0)" ::: "memory"); }
            asm volatile("s_waitcnt lgkmcnt(0)" ::: "memory");
            __builtin_amdgcn_sched_barrier(0);
            __builtin_amdgcn_s_barrier();
        }
    }

    // ---- epilogue: acc -> Cb[64 b][16 o][8 i] (overlay A), 32-B i-run stores ----
    // C/D layout (m89): col = lane&15 (=o), row = (lane>>4)*4 + reg (=b within 16)
    float* Cb = (float*)smem;
    #pragma unroll
    for (int p = 0; p < 2; ++p) {
        if (p) __syncthreads();
        #pragma unroll
        for (int mm = 0; mm < 4; ++mm) {
            #pragma unroll
            for (int j = 0; j < 4; ++j) {
                const int b_loc = mm * 16 + l4 * 4 + j;
                Cb[(b_loc * 16 + l16) * 8 + wid] = acc[p * 4 + mm][j];
            }
        }
        __syncthreads();
        #pragma unroll
        for (int s2 = 0; s2 < 2; ++s2) {
            const int e = t * 2 + s2;
            const int b_loc = e >> 4, o = e & 15;
            const float* cb = &Cb[(b_loc * 16 + o) * 8];
            f32x4 v0 = *(const f32x4*)cb;
            f32x4 v1 = *(const f32x4*)(cb + 4);
            const float* bp = &bias[(size_t)(o0 + o) * LOUT + i0];
            f32x4 bv0 = *(const f32x4*)bp;
            f32x4 bv1 = *(const f32x4*)(bp + 4);
            float* op = &out[((size_t)(p * 64 + b_loc) * 64 + o0 + o) * LOUT + i0];
            *(f32x4*)op       = v0 + 64.0f * bv0;
            *(f32x4*)(op + 4) = v1 + 64.0f * bv1;
        }
    }
#undef ISSUE_W
#undef CVT_W
#undef ISSUE_A
#undef COMPUTE
}

// ---------------- fallback (tiny ws): direct scattered-read GEMM ----------------
__global__ __launch_bounds__(512, 4) void lc1d_legacy(
    const float* __restrict__ x, const float* __restrict__ w,
    const float* __restrict__ bias, float* __restrict__ out)
{
    const int i    = ((int)(blockIdx.x & 7)) * 127 + ((int)blockIdx.x >> 3);
    const int tid  = threadIdx.x;
    const int lane = tid & 63;
    const int wid  = tid >> 6;
    const int wm   = wid >> 1;
    const int wn   = wid & 1;
    const int l16  = lane & 15;
    const int l4   = lane >> 4;

    __shared__ unsigned short Alds[128][40];
    __shared__ unsigned short Blds[64][40];

    f32x4 acc[2][2];
    #pragma unroll
    for (int a = 0; a < 2; ++a)
        #pragma unroll
        for (int b = 0; b < 2; ++b)
            acc[a][b] = (f32x4){0.f, 0.f, 0.f, 0.f};

    for (int tch = 0; tch < 18; ++tch) {
        const int q0 = tch * 32;
        #pragma unroll
        for (int j = 0; j < 4; ++j) {
            int e = tid + j * 512;
            int o = e >> 5, qq = e & 31;
            int q = q0 + qq;
            int c = q / 9, k = q - 9 * c;
            Blds[o][qq] = f2bf(w[((size_t)(o * 64 + c) * LOUT + i) * 9 + k]);
        }
        #pragma unroll
        for (int j = 0; j < 8; ++j) {
            int e = tid + j * 512;
            int b = e >> 5, qq = e & 31;
            int q = q0 + qq;
            int c = q / 9, k = q - 9 * c;
            Alds[b][qq] = f2bf(x[(size_t)(b * 64 + c) * LIN + i + k]);
        }
        __syncthreads();
        bf16x8 af[2], bfr[2];
        #pragma unroll
        for (int mf = 0; mf < 2; ++mf)
            af[mf] = *reinterpret_cast<const bf16x8*>(&Alds[wm * 32 + mf * 16 + l16][l4 * 8]);
        #pragma unroll
        for (int nf = 0; nf < 2; ++nf)
            bfr[nf] = *reinterpret_cast<const bf16x8*>(&Blds[wn * 32 + nf * 16 + l16][l4 * 8]);
        #pragma unroll
        for (int mf = 0; mf < 2; ++mf)
            #pragma unroll
            for (int nf = 0; nf < 2; ++nf)
                acc[mf][nf] = __builtin_amdgcn_mfma_f32_16x16x32_bf16(af[mf], bfr[nf], acc[mf][nf], 0, 0, 0);
        __syncthreads();
    }
    #pragma unroll
    for (int nf = 0; nf < 2; ++nf) {
        int o = wn * 32 + nf * 16 + l16;
        float bv = 64.0f * bias[o * LOUT + i];
        #pragma unroll
        for (int mf = 0; mf < 2; ++mf)
            #pragma unroll
            for (int j = 0; j < 4; ++j) {
                int b = wm * 32 + mf * 16 + l4 * 4 + j;
                out[((size_t)b * 64 + o) * LOUT + i] = acc[mf][nf][j] + bv;
            }
    }
}

extern "C" void kernel_launch(void* const* d_in, const int* in_sizes, int n_in,
                              void* d_out, int out_size, void* d_ws, size_t ws_size,
                              hipStream_t stream) {
    const float* x    = (const float*)d_in[0];
    const float* w    = (const float*)d_in[1];
    const float* bias = (const float*)d_in[2];
    float* out        = (float*)d_out;

    const size_t XTB = (size_t)1024 * 8192 * 2;   // 16,777,216

    if (ws_size < XTB) {
        lc1d_legacy<<<dim3(LOUT), dim3(512), 0, stream>>>(x, w, bias, out);
        return;
    }
    unsigned short* xt2 = (unsigned short*)d_ws;

    k1b<<<dim3(512), dim3(512), 0, stream>>>(x, xt2);
    kf2<<<dim3(508), dim3(512), 0, stream>>>(xt2, w, bias, out);
}